// Round 11
// baseline (101.663 us; speedup 1.0000x reference)
//
#include <hip/hip_runtime.h>

#define N_NODES 10000
#define HB 128         // histogram chunks

typedef unsigned int uint;
typedef unsigned short ushort;
typedef __attribute__((ext_vector_type(8))) short bf16x8;
typedef __attribute__((ext_vector_type(4))) float f32x4;

__device__ __forceinline__ ushort f2bf(float f) {
    uint b = __float_as_uint(f);
    b += 0x7fffu + ((b >> 16) & 1u);
    return (ushort)(b >> 16);
}

// ---- gather-mean body: returns (sum_even, sum_odd)/deg for node n (packed-uint channels) ----
__device__ __forceinline__ float2 mean_node(int n, int lane, const uint* __restrict__ f,
                                            const int* __restrict__ row_ptr,
                                            const ushort* __restrict__ csr) {
    int beg = row_ptr[n], end = row_ptr[n + 1];
    float ax0 = 0, ay0 = 0, ax1 = 0, ay1 = 0, ax2 = 0, ay2 = 0, ax3 = 0, ay3 = 0;
    int i = beg;
    for (; i + 8 <= end; i += 8) {
        int s0 = csr[i + 0];
        int s1 = csr[i + 1];
        int s2 = csr[i + 2];
        int s3 = csr[i + 3];
        int s4 = csr[i + 4];
        int s5 = csr[i + 5];
        int s6 = csr[i + 6];
        int s7 = csr[i + 7];
        uint u0 = f[s0 * 64 + lane];
        uint u1 = f[s1 * 64 + lane];
        uint u2 = f[s2 * 64 + lane];
        uint u3 = f[s3 * 64 + lane];
        uint u4 = f[s4 * 64 + lane];
        uint u5 = f[s5 * 64 + lane];
        uint u6 = f[s6 * 64 + lane];
        uint u7 = f[s7 * 64 + lane];
        ax0 += __uint_as_float(u0 << 16); ay0 += __uint_as_float(u0 & 0xffff0000u);
        ax1 += __uint_as_float(u1 << 16); ay1 += __uint_as_float(u1 & 0xffff0000u);
        ax2 += __uint_as_float(u2 << 16); ay2 += __uint_as_float(u2 & 0xffff0000u);
        ax3 += __uint_as_float(u3 << 16); ay3 += __uint_as_float(u3 & 0xffff0000u);
        ax0 += __uint_as_float(u4 << 16); ay0 += __uint_as_float(u4 & 0xffff0000u);
        ax1 += __uint_as_float(u5 << 16); ay1 += __uint_as_float(u5 & 0xffff0000u);
        ax2 += __uint_as_float(u6 << 16); ay2 += __uint_as_float(u6 & 0xffff0000u);
        ax3 += __uint_as_float(u7 << 16); ay3 += __uint_as_float(u7 & 0xffff0000u);
    }
    for (; i + 4 <= end; i += 4) {
        int s0 = csr[i + 0];
        int s1 = csr[i + 1];
        int s2 = csr[i + 2];
        int s3 = csr[i + 3];
        uint u0 = f[s0 * 64 + lane];
        uint u1 = f[s1 * 64 + lane];
        uint u2 = f[s2 * 64 + lane];
        uint u3 = f[s3 * 64 + lane];
        ax0 += __uint_as_float(u0 << 16); ay0 += __uint_as_float(u0 & 0xffff0000u);
        ax1 += __uint_as_float(u1 << 16); ay1 += __uint_as_float(u1 & 0xffff0000u);
        ax2 += __uint_as_float(u2 << 16); ay2 += __uint_as_float(u2 & 0xffff0000u);
        ax3 += __uint_as_float(u3 << 16); ay3 += __uint_as_float(u3 & 0xffff0000u);
    }
    for (; i < end; ++i) {
        int s = csr[i];
        uint u = f[s * 64 + lane];
        ax0 += __uint_as_float(u << 16); ay0 += __uint_as_float(u & 0xffff0000u);
    }
    float deg = (float)(end - beg);
    float inv = deg > 0.f ? 1.0f / deg : 0.0f;
    float2 r;
    r.x = ((ax0 + ax1) + (ax2 + ax3)) * inv;
    r.y = ((ay0 + ay1) + (ay2 + ay3)) * inv;
    return r;
}

// ---------------- fused prologue ----------------
// blocks [0, HB)            : per-chunk LDS histogram + local rank (CSR critical path, first)
// blocks [HB, HB+CAST_B)    : xb = bf16(x)   (block HB also zeroes aggv flags)
// blocks [HB+CAST_B, ...)   : W1T/W2T transpose-cast (one c per block; writes coalesced)
#define CAST_B 1250   // N_NODES*128/4 / 256
#define TCAST_B 512   // 2*65536 / 256

__global__ __launch_bounds__(256) void prep_kernel(const float* __restrict__ x,
                                                   const float* __restrict__ W1l,
                                                   const float* __restrict__ W1r,
                                                   const float* __restrict__ W2l,
                                                   const float* __restrict__ W2r,
                                                   const int* __restrict__ dst, int E, int chunk,
                                                   int* __restrict__ chunk_hist,
                                                   ushort* __restrict__ lrank,
                                                   ushort* __restrict__ xb,
                                                   ushort* __restrict__ W1T,
                                                   ushort* __restrict__ W2T,
                                                   int* __restrict__ aggv) {
    __shared__ int hist[N_NODES];   // 40 KB
    int b = blockIdx.x;
    int t = threadIdx.x;
    if (b < HB) {
        int4* h4 = (int4*)hist;
        for (int i = t; i < N_NODES / 4; i += 256) h4[i] = make_int4(0, 0, 0, 0);
        __syncthreads();
        int e0 = b * chunk;
        int e1 = e0 + chunk; if (e1 > E) e1 = E;
        for (int e = e0 + t; e < e1; e += 256) {
            int d = dst[e];
            lrank[e] = (ushort)atomicAdd(&hist[d], 1);
        }
        __syncthreads();
        int4* c4 = (int4*)(chunk_hist + b * N_NODES);
        for (int i = t; i < N_NODES / 4; i += 256) c4[i] = h4[i];
    } else if (b < HB + CAST_B) {
        if (b == HB && t < 64) aggv[t] = 0;    // zero lookback flags for csr_mid
        int i = (b - HB) * 256 + t;
        float4 v = ((const float4*)x)[i];
        ushort4 o;
        o.x = f2bf(v.x); o.y = f2bf(v.y); o.z = f2bf(v.z); o.w = f2bf(v.w);
        ((ushort4*)xb)[i] = o;
    } else {
        // transpose-cast, write-coalesced: one virtual column c per block, thread t = k.
        int id = b - HB - CAST_B;      // 0..511
        int z = id >> 8;               // 0: W1T, 1: W2T
        int c = id & 255;
        int k = t;
        if (z == 0) {
            // W1T[c][k] = k<128 ? W1l[k][c] : W1r[k-128][c]
            float v = (k < 128) ? W1l[k * 256 + c] : W1r[(k - 128) * 256 + c];
            W1T[c * 256 + k] = f2bf(v);
        } else {
            // W2T[c][k] = c<128 ? W2l[k][c] : W2r[k][c-128]
            float v = (c < 128) ? W2l[k * 128 + c] : W2r[k * 128 + (c - 128)];
            W2T[c * 256 + k] = f2bf(v);
        }
    }
}

// ---------------- CSR mid-chain, fused: colsum + scan (decoupled lookback) + offs ----------------
__global__ __launch_bounds__(256) void csr_mid_kernel(int* __restrict__ ch,
                                                      int* __restrict__ row_ptr,
                                                      int* __restrict__ aggv) {
    int b = blockIdx.x, t = threadIdx.x;
    int n = b * 256 + t;
    bool ok = n < N_NODES;
    int s = 0;
    if (ok) {
#pragma unroll 8
        for (int c = 0; c < HB; ++c) s += ch[c * N_NODES + n];
    }
    // block-wide inclusive scan
    int lane = t & 63, wid = t >> 6;
    int incl = s;
#pragma unroll
    for (int off = 1; off < 64; off <<= 1) {
        int y = __shfl_up(incl, off);
        if (lane >= off) incl += y;
    }
    __shared__ int wsum[4];
    __shared__ int sbase;
    if (lane == 63) wsum[wid] = incl;
    __syncthreads();
    int tot = wsum[0] + wsum[1] + wsum[2] + wsum[3];
    int wbase = 0;
#pragma unroll
    for (int w = 0; w < 4; ++w)
        if (w < wid) wbase += wsum[w];
    incl += wbase;
    // publish aggregate FIRST (no circular wait), then look back
    if (t == 0)
        __hip_atomic_store(&aggv[b], tot + 1, __ATOMIC_RELEASE, __HIP_MEMORY_SCOPE_AGENT);
    if (t < 64) {
        int v = 0;
        if (t < b) {
            do {
                v = __hip_atomic_load(&aggv[t], __ATOMIC_ACQUIRE, __HIP_MEMORY_SCOPE_AGENT);
            } while (v == 0);
            --v;
        }
#pragma unroll
        for (int m = 1; m < 64; m <<= 1) v += __shfl_xor(v, m);
        if (t == 0) sbase = v;
    }
    __syncthreads();
    int base = sbase;
    if (b == 0 && t == 0) row_ptr[0] = 0;
    if (ok) {
        row_ptr[n + 1] = base + incl;
        int run = base + incl - s;      // exclusive prefix = global start of node n
#pragma unroll 8
        for (int c = 0; c < HB; ++c) {
            int v = ch[c * N_NODES + n];
            ch[c * N_NODES + n] = run;
            run += v;
        }
    }
}

// ---------------- atomic-free scatter ----------------
__global__ __launch_bounds__(256) void scatter_kernel(const int* __restrict__ src,
                                                      const int* __restrict__ dst,
                                                      const ushort* __restrict__ lrank,
                                                      const int* __restrict__ off,
                                                      int E, int chunk,
                                                      ushort* __restrict__ csr) {
    int g = blockIdx.x * blockDim.x + threadIdx.x;
    int e = g * 4;
    if (e + 3 < E) {
        int b = e / chunk;                    // chunk is multiple of 4, so uniform for the 4-group
        const int* ob = off + b * N_NODES;
        int4 d = *(const int4*)&dst[e];
        int4 s = *(const int4*)&src[e];
        ushort4 r = *(const ushort4*)&lrank[e];
        csr[ob[d.x] + r.x] = (ushort)s.x;
        csr[ob[d.y] + r.y] = (ushort)s.y;
        csr[ob[d.z] + r.z] = (ushort)s.z;
        csr[ob[d.w] + r.w] = (ushort)s.w;
    } else {
        for (; e < E; ++e)
            csr[off[(e / chunk) * N_NODES + dst[e]] + lrank[e]] = (ushort)src[e];
    }
}

// ---------------- layer-2 aggregation: out += segment_mean(t) ----------------
__global__ __launch_bounds__(256) void agg_kernel(const ushort* __restrict__ feat,
                                                  const int* __restrict__ row_ptr,
                                                  const ushort* __restrict__ csr,
                                                  float* __restrict__ out) {
    int wave = threadIdx.x >> 6;
    int lane = threadIdx.x & 63;
    int n = blockIdx.x * 4 + wave;
    if (n >= N_NODES) return;
    float2 m = mean_node(n, lane, (const uint*)feat, row_ptr, csr);
    float2* o = (float2*)&out[n * 128 + lane * 2];
    float2 prev = *o;
    prev.x += m.x; prev.y += m.y;
    *o = prev;
}

// ---------------- fused mean1 + GEMM1 + GEMM2: 16-row panels ----------------
// grid = 625 blocks. Block owns rows r0..r0+15.
// phase 0: wave w computes mean1 for nodes r0+w*4..+3 -> LDS m1sh (packed bf16, uint stride 68)
// phase 1 (gemm1): h[16][256] = relu([mean1|x] @ W1T^T + b1) -> LDS hsh (stride 264)
// phase 2 (gemm2): vcols 0-127 -> t = bf16(h@W2l) ; 128-255 -> out = h@W2r + b2
__global__ __launch_bounds__(256) void gemm_fused(const ushort* __restrict__ xb,
                                                  const int* __restrict__ row_ptr,
                                                  const ushort* __restrict__ csr,
                                                  const ushort* __restrict__ W1T,
                                                  const float* __restrict__ b1,
                                                  const ushort* __restrict__ W2T,
                                                  const float* __restrict__ b2,
                                                  ushort* __restrict__ t,
                                                  float* __restrict__ out) {
    __shared__ ushort hsh[16 * 264];    // 8.25 KB
    __shared__ ushort m1sh[16 * 136];   // 4.25 KB (uint stride 68 -> bank step 4, conflict-free)
    int w = threadIdx.x >> 6, lane = threadIdx.x & 63;
    int lr = lane & 15, lg = lane >> 4;
    int r0 = blockIdx.x * 16;
    int row = r0 + lr;
    int c0 = w * 64;

    // ---- phase 0: mean1 for the block's 16 rows (wave w -> 4 nodes) ----
#pragma unroll
    for (int j = 0; j < 4; ++j) {
        int lrow = w * 4 + j;
        float2 m = mean_node(r0 + lrow, lane, (const uint*)xb, row_ptr, csr);
        ((uint*)m1sh)[lrow * 68 + lane] = (uint)f2bf(m.x) | ((uint)f2bf(m.y) << 16);
    }
    __syncthreads();

    // A fragments: mean part (k<128) from LDS, x part from global
    bf16x8 afr[8];
#pragma unroll
    for (int ks = 0; ks < 8; ++ks) {
        int k0 = ks * 32;
        if (k0 < 128)
            afr[ks] = *(const bf16x8*)&m1sh[lr * 136 + k0 + lg * 8];
        else
            afr[ks] = *(const bf16x8*)(xb + row * 128 + (k0 - 128) + lg * 8);
    }

    // ---- gemm1: 16 rows x 64 cols per wave, epilogue to LDS ----
    {
        f32x4 acc[4] = {};
#pragma unroll
        for (int ks = 0; ks < 8; ++ks) {
            int k0 = ks * 32;
#pragma unroll
            for (int cg = 0; cg < 4; ++cg) {
                int col = c0 + cg * 16 + lr;
                bf16x8 b = *(const bf16x8*)(W1T + col * 256 + k0 + lg * 8);
                acc[cg] = __builtin_amdgcn_mfma_f32_16x16x32_bf16(afr[ks], b, acc[cg], 0, 0, 0);
            }
        }
#pragma unroll
        for (int cg = 0; cg < 4; ++cg) {
            int col = c0 + cg * 16 + lr;
            float bias = b1[col];
#pragma unroll
            for (int i = 0; i < 4; ++i) {
                float v = acc[cg][i] + bias;
                v = v > 0.f ? v : 0.f;
                hsh[(lg * 4 + i) * 264 + col] = f2bf(v);
            }
        }
    }
    __syncthreads();

    // ---- gemm2 A fragments from LDS (rows lr, all 256 k) ----
    bf16x8 afr2[8];
#pragma unroll
    for (int ks = 0; ks < 8; ++ks)
        afr2[ks] = *(const bf16x8*)&hsh[lr * 264 + ks * 32 + lg * 8];

    // ---- gemm2: same 16 rows, vcols c0..c0+63 ----
    {
        f32x4 acc[4] = {};
#pragma unroll
        for (int ks = 0; ks < 8; ++ks) {
            int k0 = ks * 32;
#pragma unroll
            for (int cg = 0; cg < 4; ++cg) {
                int col = c0 + cg * 16 + lr;
                bf16x8 b = *(const bf16x8*)(W2T + col * 256 + k0 + lg * 8);
                acc[cg] = __builtin_amdgcn_mfma_f32_16x16x32_bf16(afr2[ks], b, acc[cg], 0, 0, 0);
            }
        }
#pragma unroll
        for (int cg = 0; cg < 4; ++cg) {
            int col = c0 + cg * 16 + lr;
            if (col < 128) {
#pragma unroll
                for (int i = 0; i < 4; ++i)
                    t[(r0 + lg * 4 + i) * 128 + col] = f2bf(acc[cg][i]);
            } else {
                int oc = col - 128;
                float bias = b2[oc];
#pragma unroll
                for (int i = 0; i < 4; ++i)
                    out[(r0 + lg * 4 + i) * 128 + oc] = acc[cg][i] + bias;
            }
        }
    }
}

// ---------------- launch ----------------

extern "C" void kernel_launch(void* const* d_in, const int* in_sizes, int n_in,
                              void* d_out, int out_size, void* d_ws, size_t ws_size,
                              hipStream_t stream) {
    const float* x   = (const float*)d_in[0];
    const int* edge  = (const int*)d_in[1];
    const float* W1l = (const float*)d_in[2];
    const float* W1r = (const float*)d_in[3];
    const float* b1  = (const float*)d_in[4];
    const float* W2l = (const float*)d_in[5];
    const float* W2r = (const float*)d_in[6];
    const float* b2  = (const float*)d_in[7];
    float* out = (float*)d_out;

    int E = in_sizes[1] / 2;
    const int* src = edge;
    const int* dst = edge + E;
    int chunk = (((E + HB - 1) / HB) + 3) & ~3;   // chunk multiple of 4

    // workspace layout
    ushort* tb   = (ushort*)d_ws;                         // [N,128] bf16 t (h@W2l)
    ushort* hb   = tb + (size_t)N_NODES * 128;            // [N,256] bf16 (layout spacer)
    ushort* xb   = hb + (size_t)N_NODES * 256;            // [N,128] bf16
    ushort* W1T  = xb + (size_t)N_NODES * 128;            // [256][256] bf16
    ushort* W2T  = W1T + 256 * 256;                       // [256][256] bf16
    ushort* csr  = W2T + 256 * 256;                       // [E]
    ushort* lrank= csr + E;                               // [E]
    int* chist   = (int*)(lrank + E);                     // [HB][N]
    int* row_ptr = chist + HB * N_NODES;                  // [N+1]
    int* aggv    = row_ptr + (N_NODES + 1);               // [64] lookback aggregates

    // fused prologue: hist (first, CSR critical path) + cast x (+ zero aggv) + tcast weights
    prep_kernel<<<HB + CAST_B + TCAST_B, 256, 0, stream>>>(x, W1l, W1r, W2l, W2r,
                                                           dst, E, chunk, chist, lrank,
                                                           xb, W1T, W2T, aggv);

    // CSR mid-chain: one kernel (decoupled lookback scan)
    csr_mid_kernel<<<(N_NODES + 255) / 256, 256, 0, stream>>>(chist, row_ptr, aggv);

    // scatter (atomic-free)
    scatter_kernel<<<(E / 4 + 255) / 256, 256, 0, stream>>>(src, dst, lrank, chist, E, chunk, csr);

    // fused mean1 + gemm1 + gemm2 (mean1 and h stay in LDS)
    gemm_fused<<<N_NODES / 16, 256, 0, stream>>>(xb, row_ptr, csr, W1T, b1, W2T, b2, tb, out);

    // layer 2 aggregation: out += segment_mean(t)
    agg_kernel<<<(N_NODES + 3) / 4, 256, 0, stream>>>(tb, row_ptr, csr, out);
}

// Round 12
// 101.437 us; speedup vs baseline: 1.0022x; 1.0022x over previous
//
#include <hip/hip_runtime.h>

#define N_NODES 10000
#define HB 128         // histogram chunks

typedef unsigned int uint;
typedef unsigned short ushort;
typedef __attribute__((ext_vector_type(8))) short bf16x8;
typedef __attribute__((ext_vector_type(4))) float f32x4;

__device__ __forceinline__ ushort f2bf(float f) {
    uint b = __float_as_uint(f);
    b += 0x7fffu + ((b >> 16) & 1u);
    return (ushort)(b >> 16);
}

// ---- gather-mean body: returns (sum_even, sum_odd)/deg for node n (packed-uint channels) ----
__device__ __forceinline__ float2 mean_node(int n, int lane, const uint* __restrict__ f,
                                            const int* __restrict__ row_ptr,
                                            const ushort* __restrict__ csr) {
    int beg = row_ptr[n], end = row_ptr[n + 1];
    float ax0 = 0, ay0 = 0, ax1 = 0, ay1 = 0, ax2 = 0, ay2 = 0, ax3 = 0, ay3 = 0;
    int i = beg;
    for (; i + 8 <= end; i += 8) {
        int s0 = csr[i + 0];
        int s1 = csr[i + 1];
        int s2 = csr[i + 2];
        int s3 = csr[i + 3];
        int s4 = csr[i + 4];
        int s5 = csr[i + 5];
        int s6 = csr[i + 6];
        int s7 = csr[i + 7];
        uint u0 = f[s0 * 64 + lane];
        uint u1 = f[s1 * 64 + lane];
        uint u2 = f[s2 * 64 + lane];
        uint u3 = f[s3 * 64 + lane];
        uint u4 = f[s4 * 64 + lane];
        uint u5 = f[s5 * 64 + lane];
        uint u6 = f[s6 * 64 + lane];
        uint u7 = f[s7 * 64 + lane];
        ax0 += __uint_as_float(u0 << 16); ay0 += __uint_as_float(u0 & 0xffff0000u);
        ax1 += __uint_as_float(u1 << 16); ay1 += __uint_as_float(u1 & 0xffff0000u);
        ax2 += __uint_as_float(u2 << 16); ay2 += __uint_as_float(u2 & 0xffff0000u);
        ax3 += __uint_as_float(u3 << 16); ay3 += __uint_as_float(u3 & 0xffff0000u);
        ax0 += __uint_as_float(u4 << 16); ay0 += __uint_as_float(u4 & 0xffff0000u);
        ax1 += __uint_as_float(u5 << 16); ay1 += __uint_as_float(u5 & 0xffff0000u);
        ax2 += __uint_as_float(u6 << 16); ay2 += __uint_as_float(u6 & 0xffff0000u);
        ax3 += __uint_as_float(u7 << 16); ay3 += __uint_as_float(u7 & 0xffff0000u);
    }
    for (; i + 4 <= end; i += 4) {
        int s0 = csr[i + 0];
        int s1 = csr[i + 1];
        int s2 = csr[i + 2];
        int s3 = csr[i + 3];
        uint u0 = f[s0 * 64 + lane];
        uint u1 = f[s1 * 64 + lane];
        uint u2 = f[s2 * 64 + lane];
        uint u3 = f[s3 * 64 + lane];
        ax0 += __uint_as_float(u0 << 16); ay0 += __uint_as_float(u0 & 0xffff0000u);
        ax1 += __uint_as_float(u1 << 16); ay1 += __uint_as_float(u1 & 0xffff0000u);
        ax2 += __uint_as_float(u2 << 16); ay2 += __uint_as_float(u2 & 0xffff0000u);
        ax3 += __uint_as_float(u3 << 16); ay3 += __uint_as_float(u3 & 0xffff0000u);
    }
    for (; i < end; ++i) {
        int s = csr[i];
        uint u = f[s * 64 + lane];
        ax0 += __uint_as_float(u << 16); ay0 += __uint_as_float(u & 0xffff0000u);
    }
    float deg = (float)(end - beg);
    float inv = deg > 0.f ? 1.0f / deg : 0.0f;
    float2 r;
    r.x = ((ax0 + ax1) + (ax2 + ax3)) * inv;
    r.y = ((ay0 + ay1) + (ay2 + ay3)) * inv;
    return r;
}

// ---------------- fused prologue ----------------
// blocks [0, HB)            : per-chunk LDS histogram + local rank (CSR critical path, first)
// blocks [HB, HB+CAST_B)    : xb = bf16(x)   (block HB also zeroes aggv flags)
// blocks [HB+CAST_B, ...)   : W1T/W2T transpose-cast (one c per block; writes coalesced)
#define CAST_B 1250   // N_NODES*128/4 / 256
#define TCAST_B 512   // 2*65536 / 256

__global__ __launch_bounds__(256) void prep_kernel(const float* __restrict__ x,
                                                   const float* __restrict__ W1l,
                                                   const float* __restrict__ W1r,
                                                   const float* __restrict__ W2l,
                                                   const float* __restrict__ W2r,
                                                   const int* __restrict__ dst, int E, int chunk,
                                                   int* __restrict__ chunk_hist,
                                                   ushort* __restrict__ lrank,
                                                   ushort* __restrict__ xb,
                                                   ushort* __restrict__ W1T,
                                                   ushort* __restrict__ W2T,
                                                   int* __restrict__ aggv) {
    __shared__ int hist[N_NODES];   // 40 KB
    int b = blockIdx.x;
    int t = threadIdx.x;
    if (b < HB) {
        int4* h4 = (int4*)hist;
        for (int i = t; i < N_NODES / 4; i += 256) h4[i] = make_int4(0, 0, 0, 0);
        __syncthreads();
        int e0 = b * chunk;
        int e1 = e0 + chunk; if (e1 > E) e1 = E;
        for (int e = e0 + t; e < e1; e += 256) {
            int d = dst[e];
            lrank[e] = (ushort)atomicAdd(&hist[d], 1);
        }
        __syncthreads();
        int4* c4 = (int4*)(chunk_hist + b * N_NODES);
        for (int i = t; i < N_NODES / 4; i += 256) c4[i] = h4[i];
    } else if (b < HB + CAST_B) {
        if (b == HB && t < 64) aggv[t] = 0;    // zero lookback flags for csr_mid
        int i = (b - HB) * 256 + t;
        float4 v = ((const float4*)x)[i];
        ushort4 o;
        o.x = f2bf(v.x); o.y = f2bf(v.y); o.z = f2bf(v.z); o.w = f2bf(v.w);
        ((ushort4*)xb)[i] = o;
    } else {
        // transpose-cast, write-coalesced: one virtual column c per block, thread t = k.
        int id = b - HB - CAST_B;      // 0..511
        int z = id >> 8;               // 0: W1T, 1: W2T
        int c = id & 255;
        int k = t;
        if (z == 0) {
            // W1T[c][k] = k<128 ? W1l[k][c] : W1r[k-128][c]
            float v = (k < 128) ? W1l[k * 256 + c] : W1r[(k - 128) * 256 + c];
            W1T[c * 256 + k] = f2bf(v);
        } else {
            // W2T[c][k] = c<128 ? W2l[k][c] : W2r[k][c-128]
            float v = (c < 128) ? W2l[k * 128 + c] : W2r[k * 128 + (c - 128)];
            W2T[c * 256 + k] = f2bf(v);
        }
    }
}

// ---------------- CSR mid-chain, fused: colsum + scan (decoupled lookback) + offs ----------------
__global__ __launch_bounds__(256) void csr_mid_kernel(int* __restrict__ ch,
                                                      int* __restrict__ row_ptr,
                                                      int* __restrict__ aggv) {
    int b = blockIdx.x, t = threadIdx.x;
    int n = b * 256 + t;
    bool ok = n < N_NODES;
    int s = 0;
    if (ok) {
#pragma unroll 8
        for (int c = 0; c < HB; ++c) s += ch[c * N_NODES + n];
    }
    // block-wide inclusive scan
    int lane = t & 63, wid = t >> 6;
    int incl = s;
#pragma unroll
    for (int off = 1; off < 64; off <<= 1) {
        int y = __shfl_up(incl, off);
        if (lane >= off) incl += y;
    }
    __shared__ int wsum[4];
    __shared__ int sbase;
    if (lane == 63) wsum[wid] = incl;
    __syncthreads();
    int tot = wsum[0] + wsum[1] + wsum[2] + wsum[3];
    int wbase = 0;
#pragma unroll
    for (int w = 0; w < 4; ++w)
        if (w < wid) wbase += wsum[w];
    incl += wbase;
    // publish aggregate FIRST (no circular wait), then look back
    if (t == 0)
        __hip_atomic_store(&aggv[b], tot + 1, __ATOMIC_RELEASE, __HIP_MEMORY_SCOPE_AGENT);
    if (t < 64) {
        int v = 0;
        if (t < b) {
            do {
                v = __hip_atomic_load(&aggv[t], __ATOMIC_ACQUIRE, __HIP_MEMORY_SCOPE_AGENT);
            } while (v == 0);
            --v;
        }
#pragma unroll
        for (int m = 1; m < 64; m <<= 1) v += __shfl_xor(v, m);
        if (t == 0) sbase = v;
    }
    __syncthreads();
    int base = sbase;
    if (b == 0 && t == 0) row_ptr[0] = 0;
    if (ok) {
        row_ptr[n + 1] = base + incl;
        int run = base + incl - s;      // exclusive prefix = global start of node n
#pragma unroll 8
        for (int c = 0; c < HB; ++c) {
            int v = ch[c * N_NODES + n];
            ch[c * N_NODES + n] = run;
            run += v;
        }
    }
}

// ---------------- atomic-free scatter ----------------
__global__ __launch_bounds__(256) void scatter_kernel(const int* __restrict__ src,
                                                      const int* __restrict__ dst,
                                                      const ushort* __restrict__ lrank,
                                                      const int* __restrict__ off,
                                                      int E, int chunk,
                                                      ushort* __restrict__ csr) {
    int g = blockIdx.x * blockDim.x + threadIdx.x;
    int e = g * 4;
    if (e + 3 < E) {
        int b = e / chunk;                    // chunk is multiple of 4, so uniform for the 4-group
        const int* ob = off + b * N_NODES;
        int4 d = *(const int4*)&dst[e];
        int4 s = *(const int4*)&src[e];
        ushort4 r = *(const ushort4*)&lrank[e];
        csr[ob[d.x] + r.x] = (ushort)s.x;
        csr[ob[d.y] + r.y] = (ushort)s.y;
        csr[ob[d.z] + r.z] = (ushort)s.z;
        csr[ob[d.w] + r.w] = (ushort)s.w;
    } else {
        for (; e < E; ++e)
            csr[off[(e / chunk) * N_NODES + dst[e]] + lrank[e]] = (ushort)src[e];
    }
}

// ---------------- layer-2 aggregation: out += segment_mean(t) ----------------
__global__ __launch_bounds__(256) void agg_kernel(const ushort* __restrict__ feat,
                                                  const int* __restrict__ row_ptr,
                                                  const ushort* __restrict__ csr,
                                                  float* __restrict__ out) {
    int wave = threadIdx.x >> 6;
    int lane = threadIdx.x & 63;
    int n = blockIdx.x * 4 + wave;
    if (n >= N_NODES) return;
    float2 m = mean_node(n, lane, (const uint*)feat, row_ptr, csr);
    float2* o = (float2*)&out[n * 128 + lane * 2];
    float2 prev = *o;
    prev.x += m.x; prev.y += m.y;
    *o = prev;
}

// ---------------- fused mean1 + GEMM1 + GEMM2: 16-row panels, 16 waves ----------------
// grid = 625 blocks x 1024 threads. Block owns rows r0..r0+15.
// phase 0: wave w computes mean1 for ONE node r0+w -> LDS m1sh  (10000 gather waves total)
// phase 1 (gemm1): wave w owns 16-col strip c0=w*16: h = relu([mean1|x]@W1T^T+b1) -> LDS hsh
// phase 2 (gemm2): same strip; waves 0-7 -> t = bf16(h@W2l); waves 8-15 -> out = h@W2r+b2
__global__ __launch_bounds__(1024, 8) void gemm_fused(const ushort* __restrict__ xb,
                                                      const int* __restrict__ row_ptr,
                                                      const ushort* __restrict__ csr,
                                                      const ushort* __restrict__ W1T,
                                                      const float* __restrict__ b1,
                                                      const ushort* __restrict__ W2T,
                                                      const float* __restrict__ b2,
                                                      ushort* __restrict__ t,
                                                      float* __restrict__ out) {
    __shared__ ushort hsh[16 * 264];    // 8.25 KB
    __shared__ ushort m1sh[16 * 136];   // 4.25 KB
    int w = threadIdx.x >> 6, lane = threadIdx.x & 63;
    int lr = lane & 15, lg = lane >> 4;
    int r0 = blockIdx.x * 16;
    int row = r0 + lr;
    int c0 = w * 16;   // this wave's 16-column strip
    int col = c0 + lr;

    // ---- phase 0: mean1 for node r0+w (one node per wave) ----
    {
        float2 m = mean_node(r0 + w, lane, (const uint*)xb, row_ptr, csr);
        ((uint*)m1sh)[w * 68 + lane] = (uint)f2bf(m.x) | ((uint)f2bf(m.y) << 16);
    }
    __syncthreads();

    // A fragments: mean part (k<128) from LDS, x part from global (L1-broadcast across waves)
    bf16x8 afr[8];
#pragma unroll
    for (int ks = 0; ks < 8; ++ks) {
        int k0 = ks * 32;
        if (k0 < 128)
            afr[ks] = *(const bf16x8*)&m1sh[lr * 136 + k0 + lg * 8];
        else
            afr[ks] = *(const bf16x8*)(xb + row * 128 + (k0 - 128) + lg * 8);
    }

    // ---- gemm1: 16 rows x 16 cols per wave, epilogue to LDS ----
    {
        f32x4 acc = {};
#pragma unroll
        for (int ks = 0; ks < 8; ++ks) {
            int k0 = ks * 32;
            bf16x8 b = *(const bf16x8*)(W1T + col * 256 + k0 + lg * 8);
            acc = __builtin_amdgcn_mfma_f32_16x16x32_bf16(afr[ks], b, acc, 0, 0, 0);
        }
        float bias = b1[col];
#pragma unroll
        for (int i = 0; i < 4; ++i) {
            float v = acc[i] + bias;
            v = v > 0.f ? v : 0.f;
            hsh[(lg * 4 + i) * 264 + col] = f2bf(v);
        }
    }
    __syncthreads();

    // ---- gemm2 A fragments from LDS (rows lr, all 256 k) ----
    bf16x8 afr2[8];
#pragma unroll
    for (int ks = 0; ks < 8; ++ks)
        afr2[ks] = *(const bf16x8*)&hsh[lr * 264 + ks * 32 + lg * 8];

    // ---- gemm2: same 16 rows, cols c0..c0+15 ----
    {
        f32x4 acc = {};
#pragma unroll
        for (int ks = 0; ks < 8; ++ks) {
            int k0 = ks * 32;
            bf16x8 b = *(const bf16x8*)(W2T + col * 256 + k0 + lg * 8);
            acc = __builtin_amdgcn_mfma_f32_16x16x32_bf16(afr2[ks], b, acc, 0, 0, 0);
        }
        if (col < 128) {   // waves 0-7: wave-uniform branch
#pragma unroll
            for (int i = 0; i < 4; ++i)
                t[(r0 + lg * 4 + i) * 128 + col] = f2bf(acc[i]);
        } else {           // waves 8-15
            int oc = col - 128;
            float bias = b2[oc];
#pragma unroll
            for (int i = 0; i < 4; ++i)
                out[(r0 + lg * 4 + i) * 128 + oc] = acc[i] + bias;
        }
    }
}

// ---------------- launch ----------------

extern "C" void kernel_launch(void* const* d_in, const int* in_sizes, int n_in,
                              void* d_out, int out_size, void* d_ws, size_t ws_size,
                              hipStream_t stream) {
    const float* x   = (const float*)d_in[0];
    const int* edge  = (const int*)d_in[1];
    const float* W1l = (const float*)d_in[2];
    const float* W1r = (const float*)d_in[3];
    const float* b1  = (const float*)d_in[4];
    const float* W2l = (const float*)d_in[5];
    const float* W2r = (const float*)d_in[6];
    const float* b2  = (const float*)d_in[7];
    float* out = (float*)d_out;

    int E = in_sizes[1] / 2;
    const int* src = edge;
    const int* dst = edge + E;
    int chunk = (((E + HB - 1) / HB) + 3) & ~3;   // chunk multiple of 4

    // workspace layout
    ushort* tb   = (ushort*)d_ws;                         // [N,128] bf16 t (h@W2l)
    ushort* hb   = tb + (size_t)N_NODES * 128;            // [N,256] bf16 (layout spacer)
    ushort* xb   = hb + (size_t)N_NODES * 256;            // [N,128] bf16
    ushort* W1T  = xb + (size_t)N_NODES * 128;            // [256][256] bf16
    ushort* W2T  = W1T + 256 * 256;                       // [256][256] bf16
    ushort* csr  = W2T + 256 * 256;                       // [E]
    ushort* lrank= csr + E;                               // [E]
    int* chist   = (int*)(lrank + E);                     // [HB][N]
    int* row_ptr = chist + HB * N_NODES;                  // [N+1]
    int* aggv    = row_ptr + (N_NODES + 1);               // [64] lookback aggregates

    // fused prologue: hist (first, CSR critical path) + cast x (+ zero aggv) + tcast weights
    prep_kernel<<<HB + CAST_B + TCAST_B, 256, 0, stream>>>(x, W1l, W1r, W2l, W2r,
                                                           dst, E, chunk, chist, lrank,
                                                           xb, W1T, W2T, aggv);

    // CSR mid-chain: one kernel (decoupled lookback scan)
    csr_mid_kernel<<<(N_NODES + 255) / 256, 256, 0, stream>>>(chist, row_ptr, aggv);

    // scatter (atomic-free)
    scatter_kernel<<<(E / 4 + 255) / 256, 256, 0, stream>>>(src, dst, lrank, chist, E, chunk, csr);

    // fused mean1 + gemm1 + gemm2 (mean1 and h stay in LDS), 16 waves/block
    gemm_fused<<<N_NODES / 16, 1024, 0, stream>>>(xb, row_ptr, csr, W1T, b1, W2T, b2, tb, out);

    // layer 2 aggregation: out += segment_mean(t)
    agg_kernel<<<(N_NODES + 3) / 4, 256, 0, stream>>>(tb, row_ptr, csr, out);
}

// Round 13
// 98.187 us; speedup vs baseline: 1.0354x; 1.0331x over previous
//
#include <hip/hip_runtime.h>

#define N_NODES 10000
#define HB 128         // histogram chunks

typedef unsigned int uint;
typedef unsigned short ushort;
typedef __attribute__((ext_vector_type(8))) short bf16x8;
typedef __attribute__((ext_vector_type(4))) float f32x4;

__device__ __forceinline__ ushort f2bf(float f) {
    uint b = __float_as_uint(f);
    b += 0x7fffu + ((b >> 16) & 1u);
    return (ushort)(b >> 16);
}

// ---- wide gather-sum: 16B/lane loads, 4 edge-rows (1KB) per load instruction ----
// lane l: edge-class l>>4, channels 8*(l&15)..+7. After the xor-butterfly all lanes
// hold the full channel-span sums (replicated across the 4 classes). acc[8] f32.
__device__ __forceinline__ void gather_sum16(int n, int lane, const ushort* __restrict__ feat,
                                             const int* __restrict__ row_ptr,
                                             const ushort* __restrict__ csr,
                                             float* acc, float* invdeg) {
    int beg = row_ptr[n], end = row_ptr[n + 1];
    int ch0 = (lane & 15) * 8;
    int eo = lane >> 4;
#pragma unroll
    for (int j = 0; j < 8; ++j) acc[j] = 0.f;
    for (int i = beg; i < end; i += 16) {
        int e0 = i + eo, e1 = e0 + 4, e2 = e0 + 8, e3 = e0 + 12;
        bf16x8 v0 = {}, v1 = {}, v2 = {}, v3 = {};
        if (e0 < end) { int s = csr[e0]; v0 = *(const bf16x8*)&feat[s * 128 + ch0]; }
        if (e1 < end) { int s = csr[e1]; v1 = *(const bf16x8*)&feat[s * 128 + ch0]; }
        if (e2 < end) { int s = csr[e2]; v2 = *(const bf16x8*)&feat[s * 128 + ch0]; }
        if (e3 < end) { int s = csr[e3]; v3 = *(const bf16x8*)&feat[s * 128 + ch0]; }
#pragma unroll
        for (int j = 0; j < 8; ++j) {
            acc[j] += __uint_as_float((uint)(ushort)v0[j] << 16);
            acc[j] += __uint_as_float((uint)(ushort)v1[j] << 16);
            acc[j] += __uint_as_float((uint)(ushort)v2[j] << 16);
            acc[j] += __uint_as_float((uint)(ushort)v3[j] << 16);
        }
    }
    // reduce the 4 edge-classes (lanes l, l+16, l+32, l+48 share a channel-span)
#pragma unroll
    for (int j = 0; j < 8; ++j) {
        acc[j] += __shfl_xor(acc[j], 16);
        acc[j] += __shfl_xor(acc[j], 32);
    }
    float deg = (float)(end - beg);
    *invdeg = deg > 0.f ? 1.0f / deg : 0.0f;
}

// ---------------- fused prologue ----------------
// blocks [0, HB)            : per-chunk LDS histogram + local rank (CSR critical path, first)
// blocks [HB, HB+CAST_B)    : xb = bf16(x)   (block HB also zeroes aggv flags)
// blocks [HB+CAST_B, ...)   : W1T/W2T transpose-cast (one c per block; writes coalesced)
#define CAST_B 1250   // N_NODES*128/4 / 256
#define TCAST_B 512   // 2*65536 / 256

__global__ __launch_bounds__(256) void prep_kernel(const float* __restrict__ x,
                                                   const float* __restrict__ W1l,
                                                   const float* __restrict__ W1r,
                                                   const float* __restrict__ W2l,
                                                   const float* __restrict__ W2r,
                                                   const int* __restrict__ dst, int E, int chunk,
                                                   int* __restrict__ chunk_hist,
                                                   ushort* __restrict__ lrank,
                                                   ushort* __restrict__ xb,
                                                   ushort* __restrict__ W1T,
                                                   ushort* __restrict__ W2T,
                                                   int* __restrict__ aggv) {
    __shared__ int hist[N_NODES];   // 40 KB
    int b = blockIdx.x;
    int t = threadIdx.x;
    if (b < HB) {
        int4* h4 = (int4*)hist;
        for (int i = t; i < N_NODES / 4; i += 256) h4[i] = make_int4(0, 0, 0, 0);
        __syncthreads();
        int e0 = b * chunk;
        int e1 = e0 + chunk; if (e1 > E) e1 = E;
        for (int e = e0 + t; e < e1; e += 256) {
            int d = dst[e];
            lrank[e] = (ushort)atomicAdd(&hist[d], 1);
        }
        __syncthreads();
        int4* c4 = (int4*)(chunk_hist + b * N_NODES);
        for (int i = t; i < N_NODES / 4; i += 256) c4[i] = h4[i];
    } else if (b < HB + CAST_B) {
        if (b == HB && t < 64) aggv[t] = 0;    // zero lookback flags for csr_mid
        int i = (b - HB) * 256 + t;
        float4 v = ((const float4*)x)[i];
        ushort4 o;
        o.x = f2bf(v.x); o.y = f2bf(v.y); o.z = f2bf(v.z); o.w = f2bf(v.w);
        ((ushort4*)xb)[i] = o;
    } else {
        // transpose-cast, write-coalesced: one virtual column c per block, thread t = k.
        int id = b - HB - CAST_B;      // 0..511
        int z = id >> 8;               // 0: W1T, 1: W2T
        int c = id & 255;
        int k = t;
        if (z == 0) {
            // W1T[c][k] = k<128 ? W1l[k][c] : W1r[k-128][c]
            float v = (k < 128) ? W1l[k * 256 + c] : W1r[(k - 128) * 256 + c];
            W1T[c * 256 + k] = f2bf(v);
        } else {
            // W2T[c][k] = c<128 ? W2l[k][c] : W2r[k][c-128]
            float v = (c < 128) ? W2l[k * 128 + c] : W2r[k * 128 + (c - 128)];
            W2T[c * 256 + k] = f2bf(v);
        }
    }
}

// ---------------- CSR mid-chain, fused: colsum + scan (decoupled lookback) + offs ----------------
__global__ __launch_bounds__(256) void csr_mid_kernel(int* __restrict__ ch,
                                                      int* __restrict__ row_ptr,
                                                      int* __restrict__ aggv) {
    int b = blockIdx.x, t = threadIdx.x;
    int n = b * 256 + t;
    bool ok = n < N_NODES;
    int s = 0;
    if (ok) {
#pragma unroll 8
        for (int c = 0; c < HB; ++c) s += ch[c * N_NODES + n];
    }
    // block-wide inclusive scan
    int lane = t & 63, wid = t >> 6;
    int incl = s;
#pragma unroll
    for (int off = 1; off < 64; off <<= 1) {
        int y = __shfl_up(incl, off);
        if (lane >= off) incl += y;
    }
    __shared__ int wsum[4];
    __shared__ int sbase;
    if (lane == 63) wsum[wid] = incl;
    __syncthreads();
    int tot = wsum[0] + wsum[1] + wsum[2] + wsum[3];
    int wbase = 0;
#pragma unroll
    for (int w = 0; w < 4; ++w)
        if (w < wid) wbase += wsum[w];
    incl += wbase;
    // publish aggregate FIRST (no circular wait), then look back
    if (t == 0)
        __hip_atomic_store(&aggv[b], tot + 1, __ATOMIC_RELEASE, __HIP_MEMORY_SCOPE_AGENT);
    if (t < 64) {
        int v = 0;
        if (t < b) {
            do {
                v = __hip_atomic_load(&aggv[t], __ATOMIC_ACQUIRE, __HIP_MEMORY_SCOPE_AGENT);
            } while (v == 0);
            --v;
        }
#pragma unroll
        for (int m = 1; m < 64; m <<= 1) v += __shfl_xor(v, m);
        if (t == 0) sbase = v;
    }
    __syncthreads();
    int base = sbase;
    if (b == 0 && t == 0) row_ptr[0] = 0;
    if (ok) {
        row_ptr[n + 1] = base + incl;
        int run = base + incl - s;      // exclusive prefix = global start of node n
#pragma unroll 8
        for (int c = 0; c < HB; ++c) {
            int v = ch[c * N_NODES + n];
            ch[c * N_NODES + n] = run;
            run += v;
        }
    }
}

// ---------------- atomic-free scatter ----------------
__global__ __launch_bounds__(256) void scatter_kernel(const int* __restrict__ src,
                                                      const int* __restrict__ dst,
                                                      const ushort* __restrict__ lrank,
                                                      const int* __restrict__ off,
                                                      int E, int chunk,
                                                      ushort* __restrict__ csr) {
    int g = blockIdx.x * blockDim.x + threadIdx.x;
    int e = g * 4;
    if (e + 3 < E) {
        int b = e / chunk;                    // chunk is multiple of 4, so uniform for the 4-group
        const int* ob = off + b * N_NODES;
        int4 d = *(const int4*)&dst[e];
        int4 s = *(const int4*)&src[e];
        ushort4 r = *(const ushort4*)&lrank[e];
        csr[ob[d.x] + r.x] = (ushort)s.x;
        csr[ob[d.y] + r.y] = (ushort)s.y;
        csr[ob[d.z] + r.z] = (ushort)s.z;
        csr[ob[d.w] + r.w] = (ushort)s.w;
    } else {
        for (; e < E; ++e)
            csr[off[(e / chunk) * N_NODES + dst[e]] + lrank[e]] = (ushort)src[e];
    }
}

// ---------------- layer-2 aggregation: out += segment_mean(t) ----------------
__global__ __launch_bounds__(256) void agg_kernel(const ushort* __restrict__ feat,
                                                  const int* __restrict__ row_ptr,
                                                  const ushort* __restrict__ csr,
                                                  float* __restrict__ out) {
    int wave = threadIdx.x >> 6;
    int lane = threadIdx.x & 63;
    int n = blockIdx.x * 4 + wave;
    if (n >= N_NODES) return;
    float acc[8], inv;
    gather_sum16(n, lane, feat, row_ptr, csr, acc, &inv);
    if ((lane >> 4) == 0) {   // lanes 0-15: 32B contiguous per lane, 512B per row
        float4* o = (float4*)&out[n * 128 + (lane & 15) * 8];
        float4 a = o[0], b = o[1];
        a.x += acc[0] * inv; a.y += acc[1] * inv; a.z += acc[2] * inv; a.w += acc[3] * inv;
        b.x += acc[4] * inv; b.y += acc[5] * inv; b.z += acc[6] * inv; b.w += acc[7] * inv;
        o[0] = a; o[1] = b;
    }
}

// ---------------- fused mean1 + GEMM1 + GEMM2: 16-row panels, 16 waves ----------------
// grid = 625 blocks x 1024 threads. Block owns rows r0..r0+15.
// phase 0: wave w computes mean1 for ONE node r0+w -> LDS m1sh  (10000 gather waves total)
// phase 1 (gemm1): wave w owns 16-col strip c0=w*16: h = relu([mean1|x]@W1T^T+b1) -> LDS hsh
// phase 2 (gemm2): same strip; waves 0-7 -> t = bf16(h@W2l); waves 8-15 -> out = h@W2r+b2
__global__ __launch_bounds__(1024, 8) void gemm_fused(const ushort* __restrict__ xb,
                                                      const int* __restrict__ row_ptr,
                                                      const ushort* __restrict__ csr,
                                                      const ushort* __restrict__ W1T,
                                                      const float* __restrict__ b1,
                                                      const ushort* __restrict__ W2T,
                                                      const float* __restrict__ b2,
                                                      ushort* __restrict__ t,
                                                      float* __restrict__ out) {
    __shared__ ushort hsh[16 * 264];    // 8.25 KB
    __shared__ ushort m1sh[16 * 136];   // 4.25 KB
    int w = threadIdx.x >> 6, lane = threadIdx.x & 63;
    int lr = lane & 15, lg = lane >> 4;
    int r0 = blockIdx.x * 16;
    int row = r0 + lr;
    int c0 = w * 16;   // this wave's 16-column strip
    int col = c0 + lr;

    // ---- phase 0: mean1 for node r0+w (one node per wave, 16B/lane gather) ----
    {
        float acc[8], inv;
        gather_sum16(r0 + w, lane, xb, row_ptr, csr, acc, &inv);
        if (lg == 0) {   // lanes 0-15: pack 8 channels -> uint4, 16B contiguous per lane
            uint4 u;
            u.x = (uint)f2bf(acc[0] * inv) | ((uint)f2bf(acc[1] * inv) << 16);
            u.y = (uint)f2bf(acc[2] * inv) | ((uint)f2bf(acc[3] * inv) << 16);
            u.z = (uint)f2bf(acc[4] * inv) | ((uint)f2bf(acc[5] * inv) << 16);
            u.w = (uint)f2bf(acc[6] * inv) | ((uint)f2bf(acc[7] * inv) << 16);
            *(uint4*)&((uint*)m1sh)[w * 68 + lr * 4] = u;
        }
    }
    __syncthreads();

    // A fragments: mean part (k<128) from LDS, x part from global (L1-broadcast across waves)
    bf16x8 afr[8];
#pragma unroll
    for (int ks = 0; ks < 8; ++ks) {
        int k0 = ks * 32;
        if (k0 < 128)
            afr[ks] = *(const bf16x8*)&m1sh[lr * 136 + k0 + lg * 8];
        else
            afr[ks] = *(const bf16x8*)(xb + row * 128 + (k0 - 128) + lg * 8);
    }

    // ---- gemm1: 16 rows x 16 cols per wave, epilogue to LDS ----
    {
        f32x4 acc = {};
#pragma unroll
        for (int ks = 0; ks < 8; ++ks) {
            int k0 = ks * 32;
            bf16x8 b = *(const bf16x8*)(W1T + col * 256 + k0 + lg * 8);
            acc = __builtin_amdgcn_mfma_f32_16x16x32_bf16(afr[ks], b, acc, 0, 0, 0);
        }
        float bias = b1[col];
#pragma unroll
        for (int i = 0; i < 4; ++i) {
            float v = acc[i] + bias;
            v = v > 0.f ? v : 0.f;
            hsh[(lg * 4 + i) * 264 + col] = f2bf(v);
        }
    }
    __syncthreads();

    // ---- gemm2 A fragments from LDS (rows lr, all 256 k) ----
    bf16x8 afr2[8];
#pragma unroll
    for (int ks = 0; ks < 8; ++ks)
        afr2[ks] = *(const bf16x8*)&hsh[lr * 264 + ks * 32 + lg * 8];

    // ---- gemm2: same 16 rows, cols c0..c0+15 ----
    {
        f32x4 acc = {};
#pragma unroll
        for (int ks = 0; ks < 8; ++ks) {
            int k0 = ks * 32;
            bf16x8 b = *(const bf16x8*)(W2T + col * 256 + k0 + lg * 8);
            acc = __builtin_amdgcn_mfma_f32_16x16x32_bf16(afr2[ks], b, acc, 0, 0, 0);
        }
        if (col < 128) {   // waves 0-7: wave-uniform branch
#pragma unroll
            for (int i = 0; i < 4; ++i)
                t[(r0 + lg * 4 + i) * 128 + col] = f2bf(acc[i]);
        } else {           // waves 8-15
            int oc = col - 128;
            float bias = b2[oc];
#pragma unroll
            for (int i = 0; i < 4; ++i)
                out[(r0 + lg * 4 + i) * 128 + oc] = acc[i] + bias;
        }
    }
}

// ---------------- launch ----------------

extern "C" void kernel_launch(void* const* d_in, const int* in_sizes, int n_in,
                              void* d_out, int out_size, void* d_ws, size_t ws_size,
                              hipStream_t stream) {
    const float* x   = (const float*)d_in[0];
    const int* edge  = (const int*)d_in[1];
    const float* W1l = (const float*)d_in[2];
    const float* W1r = (const float*)d_in[3];
    const float* b1  = (const float*)d_in[4];
    const float* W2l = (const float*)d_in[5];
    const float* W2r = (const float*)d_in[6];
    const float* b2  = (const float*)d_in[7];
    float* out = (float*)d_out;

    int E = in_sizes[1] / 2;
    const int* src = edge;
    const int* dst = edge + E;
    int chunk = (((E + HB - 1) / HB) + 3) & ~3;   // chunk multiple of 4

    // workspace layout
    ushort* tb   = (ushort*)d_ws;                         // [N,128] bf16 t (h@W2l)
    ushort* hb   = tb + (size_t)N_NODES * 128;            // [N,256] bf16 (layout spacer)
    ushort* xb   = hb + (size_t)N_NODES * 256;            // [N,128] bf16
    ushort* W1T  = xb + (size_t)N_NODES * 128;            // [256][256] bf16
    ushort* W2T  = W1T + 256 * 256;                       // [256][256] bf16
    ushort* csr  = W2T + 256 * 256;                       // [E]
    ushort* lrank= csr + E;                               // [E]
    int* chist   = (int*)(lrank + E);                     // [HB][N]
    int* row_ptr = chist + HB * N_NODES;                  // [N+1]
    int* aggv    = row_ptr + (N_NODES + 1);               // [64] lookback aggregates

    // fused prologue: hist (first, CSR critical path) + cast x (+ zero aggv) + tcast weights
    prep_kernel<<<HB + CAST_B + TCAST_B, 256, 0, stream>>>(x, W1l, W1r, W2l, W2r,
                                                           dst, E, chunk, chist, lrank,
                                                           xb, W1T, W2T, aggv);

    // CSR mid-chain: one kernel (decoupled lookback scan)
    csr_mid_kernel<<<(N_NODES + 255) / 256, 256, 0, stream>>>(chist, row_ptr, aggv);

    // scatter (atomic-free)
    scatter_kernel<<<(E / 4 + 255) / 256, 256, 0, stream>>>(src, dst, lrank, chist, E, chunk, csr);

    // fused mean1 + gemm1 + gemm2 (mean1 and h stay in LDS), 16 waves/block
    gemm_fused<<<N_NODES / 16, 1024, 0, stream>>>(xb, row_ptr, csr, W1T, b1, W2T, b2, tb, out);

    // layer 2 aggregation: out += segment_mean(t)
    agg_kernel<<<(N_NODES + 3) / 4, 256, 0, stream>>>(tb, row_ptr, csr, out);
}

// Round 14
// 92.650 us; speedup vs baseline: 1.0973x; 1.0598x over previous
//
#include <hip/hip_runtime.h>

#define N_NODES 10000
#define HB 128         // histogram chunks

typedef unsigned int uint;
typedef unsigned short ushort;
typedef __attribute__((ext_vector_type(8))) short bf16x8;
typedef __attribute__((ext_vector_type(4))) float f32x4;

__device__ __forceinline__ ushort f2bf(float f) {
    uint b = __float_as_uint(f);
    b += 0x7fffu + ((b >> 16) & 1u);
    return (ushort)(b >> 16);
}

// ---- wide gather-sum, 8-deep software-pipelined ----
// lane l: edge-class l>>4, channels 8*(l&15)..+7. Per iteration: 8x16B feature loads
// (32 edges/wave) with NEXT block's csr indices issued before the accumulate, so
// index latency hides under feature latency. Full blocks unguarded; tail guarded.
#define ACCV(vv)                                                           \
    {                                                                      \
        _Pragma("unroll") for (int j = 0; j < 8; ++j)                      \
            acc[j] += __uint_as_float((uint)(ushort)vv[j] << 16);          \
    }

__device__ __forceinline__ void gather_sum16(int n, int lane, const ushort* __restrict__ feat,
                                             const int* __restrict__ row_ptr,
                                             const ushort* __restrict__ csr,
                                             float* acc, float* invdeg) {
    int beg = row_ptr[n], end = row_ptr[n + 1];
    int ch0 = (lane & 15) * 8;
    int eo = lane >> 4;
#pragma unroll
    for (int j = 0; j < 8; ++j) acc[j] = 0.f;
    float deg = (float)(end - beg);
    *invdeg = deg > 0.f ? 1.0f / deg : 0.0f;
    if (beg >= end) return;
    int last = end - 1;
    int i = beg;
    int b0 = i + eo;
    int s0 = csr[min(b0 + 0, last)];
    int s1 = csr[min(b0 + 4, last)];
    int s2 = csr[min(b0 + 8, last)];
    int s3 = csr[min(b0 + 12, last)];
    int s4 = csr[min(b0 + 16, last)];
    int s5 = csr[min(b0 + 20, last)];
    int s6 = csr[min(b0 + 24, last)];
    int s7 = csr[min(b0 + 28, last)];
    while (true) {
        // issue 8 feature loads (1KB-per-instruction across the wave)
        bf16x8 v0 = *(const bf16x8*)&feat[s0 * 128 + ch0];
        bf16x8 v1 = *(const bf16x8*)&feat[s1 * 128 + ch0];
        bf16x8 v2 = *(const bf16x8*)&feat[s2 * 128 + ch0];
        bf16x8 v3 = *(const bf16x8*)&feat[s3 * 128 + ch0];
        bf16x8 v4 = *(const bf16x8*)&feat[s4 * 128 + ch0];
        bf16x8 v5 = *(const bf16x8*)&feat[s5 * 128 + ch0];
        bf16x8 v6 = *(const bf16x8*)&feat[s6 * 128 + ch0];
        bf16x8 v7 = *(const bf16x8*)&feat[s7 * 128 + ch0];
        int inext = i + 32;
        bool more = inext < end;
        if (more) {   // prefetch next indices BEFORE consuming v's (hides index latency)
            int nb = inext + eo;
            s0 = csr[min(nb + 0, last)];
            s1 = csr[min(nb + 4, last)];
            s2 = csr[min(nb + 8, last)];
            s3 = csr[min(nb + 12, last)];
            s4 = csr[min(nb + 16, last)];
            s5 = csr[min(nb + 20, last)];
            s6 = csr[min(nb + 24, last)];
            s7 = csr[min(nb + 28, last)];
        }
        if (inext <= end) {   // full block: all 8 slots valid
            ACCV(v0) ACCV(v1) ACCV(v2) ACCV(v3)
            ACCV(v4) ACCV(v5) ACCV(v6) ACCV(v7)
        } else {              // tail: guard each slot
            int tb = i + eo;
            if (tb + 0 < end)  ACCV(v0)
            if (tb + 4 < end)  ACCV(v1)
            if (tb + 8 < end)  ACCV(v2)
            if (tb + 12 < end) ACCV(v3)
            if (tb + 16 < end) ACCV(v4)
            if (tb + 20 < end) ACCV(v5)
            if (tb + 24 < end) ACCV(v6)
            if (tb + 28 < end) ACCV(v7)
        }
        if (!more) break;
        i = inext;
    }
    // reduce the 4 edge-classes (lanes l, l+16, l+32, l+48 share a channel-span)
#pragma unroll
    for (int j = 0; j < 8; ++j) {
        acc[j] += __shfl_xor(acc[j], 16);
        acc[j] += __shfl_xor(acc[j], 32);
    }
}

// ---------------- fused prologue ----------------
// blocks [0, HB)            : per-chunk LDS histogram + local rank (CSR critical path, first)
// blocks [HB, HB+CAST_B)    : xb = bf16(x)   (block HB also zeroes aggv flags)
// blocks [HB+CAST_B, ...)   : W1T/W2T transpose-cast (one c per block; writes coalesced)
#define CAST_B 1250   // N_NODES*128/4 / 256
#define TCAST_B 512   // 2*65536 / 256

__global__ __launch_bounds__(256) void prep_kernel(const float* __restrict__ x,
                                                   const float* __restrict__ W1l,
                                                   const float* __restrict__ W1r,
                                                   const float* __restrict__ W2l,
                                                   const float* __restrict__ W2r,
                                                   const int* __restrict__ dst, int E, int chunk,
                                                   int* __restrict__ chunk_hist,
                                                   ushort* __restrict__ lrank,
                                                   ushort* __restrict__ xb,
                                                   ushort* __restrict__ W1T,
                                                   ushort* __restrict__ W2T,
                                                   int* __restrict__ aggv) {
    __shared__ int hist[N_NODES];   // 40 KB
    int b = blockIdx.x;
    int t = threadIdx.x;
    if (b < HB) {
        int4* h4 = (int4*)hist;
        for (int i = t; i < N_NODES / 4; i += 256) h4[i] = make_int4(0, 0, 0, 0);
        __syncthreads();
        int e0 = b * chunk;
        int e1 = e0 + chunk; if (e1 > E) e1 = E;
        for (int e = e0 + t; e < e1; e += 256) {
            int d = dst[e];
            lrank[e] = (ushort)atomicAdd(&hist[d], 1);
        }
        __syncthreads();
        int4* c4 = (int4*)(chunk_hist + b * N_NODES);
        for (int i = t; i < N_NODES / 4; i += 256) c4[i] = h4[i];
    } else if (b < HB + CAST_B) {
        if (b == HB && t < 64) aggv[t] = 0;    // zero lookback flags for csr_mid
        int i = (b - HB) * 256 + t;
        float4 v = ((const float4*)x)[i];
        ushort4 o;
        o.x = f2bf(v.x); o.y = f2bf(v.y); o.z = f2bf(v.z); o.w = f2bf(v.w);
        ((ushort4*)xb)[i] = o;
    } else {
        // transpose-cast, write-coalesced: one virtual column c per block, thread t = k.
        int id = b - HB - CAST_B;      // 0..511
        int z = id >> 8;               // 0: W1T, 1: W2T
        int c = id & 255;
        int k = t;
        if (z == 0) {
            // W1T[c][k] = k<128 ? W1l[k][c] : W1r[k-128][c]
            float v = (k < 128) ? W1l[k * 256 + c] : W1r[(k - 128) * 256 + c];
            W1T[c * 256 + k] = f2bf(v);
        } else {
            // W2T[c][k] = c<128 ? W2l[k][c] : W2r[k][c-128]
            float v = (c < 128) ? W2l[k * 128 + c] : W2r[k * 128 + (c - 128)];
            W2T[c * 256 + k] = f2bf(v);
        }
    }
}

// ---------------- CSR mid-chain, fused: colsum + scan (decoupled lookback) + offs ----------------
__global__ __launch_bounds__(256) void csr_mid_kernel(int* __restrict__ ch,
                                                      int* __restrict__ row_ptr,
                                                      int* __restrict__ aggv) {
    int b = blockIdx.x, t = threadIdx.x;
    int n = b * 256 + t;
    bool ok = n < N_NODES;
    int s = 0;
    if (ok) {
#pragma unroll 8
        for (int c = 0; c < HB; ++c) s += ch[c * N_NODES + n];
    }
    // block-wide inclusive scan
    int lane = t & 63, wid = t >> 6;
    int incl = s;
#pragma unroll
    for (int off = 1; off < 64; off <<= 1) {
        int y = __shfl_up(incl, off);
        if (lane >= off) incl += y;
    }
    __shared__ int wsum[4];
    __shared__ int sbase;
    if (lane == 63) wsum[wid] = incl;
    __syncthreads();
    int tot = wsum[0] + wsum[1] + wsum[2] + wsum[3];
    int wbase = 0;
#pragma unroll
    for (int w = 0; w < 4; ++w)
        if (w < wid) wbase += wsum[w];
    incl += wbase;
    // publish aggregate FIRST (no circular wait), then look back
    if (t == 0)
        __hip_atomic_store(&aggv[b], tot + 1, __ATOMIC_RELEASE, __HIP_MEMORY_SCOPE_AGENT);
    if (t < 64) {
        int v = 0;
        if (t < b) {
            do {
                v = __hip_atomic_load(&aggv[t], __ATOMIC_ACQUIRE, __HIP_MEMORY_SCOPE_AGENT);
            } while (v == 0);
            --v;
        }
#pragma unroll
        for (int m = 1; m < 64; m <<= 1) v += __shfl_xor(v, m);
        if (t == 0) sbase = v;
    }
    __syncthreads();
    int base = sbase;
    if (b == 0 && t == 0) row_ptr[0] = 0;
    if (ok) {
        row_ptr[n + 1] = base + incl;
        int run = base + incl - s;      // exclusive prefix = global start of node n
#pragma unroll 8
        for (int c = 0; c < HB; ++c) {
            int v = ch[c * N_NODES + n];
            ch[c * N_NODES + n] = run;
            run += v;
        }
    }
}

// ---------------- atomic-free scatter ----------------
__global__ __launch_bounds__(256) void scatter_kernel(const int* __restrict__ src,
                                                      const int* __restrict__ dst,
                                                      const ushort* __restrict__ lrank,
                                                      const int* __restrict__ off,
                                                      int E, int chunk,
                                                      ushort* __restrict__ csr) {
    int g = blockIdx.x * blockDim.x + threadIdx.x;
    int e = g * 4;
    if (e + 3 < E) {
        int b = e / chunk;                    // chunk is multiple of 4, so uniform for the 4-group
        const int* ob = off + b * N_NODES;
        int4 d = *(const int4*)&dst[e];
        int4 s = *(const int4*)&src[e];
        ushort4 r = *(const ushort4*)&lrank[e];
        csr[ob[d.x] + r.x] = (ushort)s.x;
        csr[ob[d.y] + r.y] = (ushort)s.y;
        csr[ob[d.z] + r.z] = (ushort)s.z;
        csr[ob[d.w] + r.w] = (ushort)s.w;
    } else {
        for (; e < E; ++e)
            csr[off[(e / chunk) * N_NODES + dst[e]] + lrank[e]] = (ushort)src[e];
    }
}

// ---------------- layer-2 aggregation: out += segment_mean(t) ----------------
__global__ __launch_bounds__(256) void agg_kernel(const ushort* __restrict__ feat,
                                                  const int* __restrict__ row_ptr,
                                                  const ushort* __restrict__ csr,
                                                  float* __restrict__ out) {
    int wave = threadIdx.x >> 6;
    int lane = threadIdx.x & 63;
    int n = blockIdx.x * 4 + wave;
    if (n >= N_NODES) return;
    float acc[8], inv;
    gather_sum16(n, lane, feat, row_ptr, csr, acc, &inv);
    if ((lane >> 4) == 0) {   // lanes 0-15: 32B contiguous per lane, 512B per row
        float4* o = (float4*)&out[n * 128 + (lane & 15) * 8];
        float4 a = o[0], b = o[1];
        a.x += acc[0] * inv; a.y += acc[1] * inv; a.z += acc[2] * inv; a.w += acc[3] * inv;
        b.x += acc[4] * inv; b.y += acc[5] * inv; b.z += acc[6] * inv; b.w += acc[7] * inv;
        o[0] = a; o[1] = b;
    }
}

// ---------------- fused mean1 + GEMM1 + GEMM2: 16-row panels, 16 waves ----------------
// grid = 625 blocks x 1024 threads. Block owns rows r0..r0+15.
// phase 0: wave w computes mean1 for ONE node r0+w -> LDS m1sh  (10000 gather waves total)
// phase 1 (gemm1): wave w owns 16-col strip c0=w*16: h = relu([mean1|x]@W1T^T+b1) -> LDS hsh
// phase 2 (gemm2): same strip; waves 0-7 -> t = bf16(h@W2l); waves 8-15 -> out = h@W2r+b2
__global__ __launch_bounds__(1024, 8) void gemm_fused(const ushort* __restrict__ xb,
                                                      const int* __restrict__ row_ptr,
                                                      const ushort* __restrict__ csr,
                                                      const ushort* __restrict__ W1T,
                                                      const float* __restrict__ b1,
                                                      const ushort* __restrict__ W2T,
                                                      const float* __restrict__ b2,
                                                      ushort* __restrict__ t,
                                                      float* __restrict__ out) {
    __shared__ ushort hsh[16 * 264];    // 8.25 KB
    __shared__ ushort m1sh[16 * 136];   // 4.25 KB
    int w = threadIdx.x >> 6, lane = threadIdx.x & 63;
    int lr = lane & 15, lg = lane >> 4;
    int r0 = blockIdx.x * 16;
    int row = r0 + lr;
    int c0 = w * 16;   // this wave's 16-column strip
    int col = c0 + lr;

    // ---- phase 0: mean1 for node r0+w (one node per wave, 8-deep 16B/lane gather) ----
    {
        float acc[8], inv;
        gather_sum16(r0 + w, lane, xb, row_ptr, csr, acc, &inv);
        if (lg == 0) {   // lanes 0-15: pack 8 channels -> uint4, 16B contiguous per lane
            uint4 u;
            u.x = (uint)f2bf(acc[0] * inv) | ((uint)f2bf(acc[1] * inv) << 16);
            u.y = (uint)f2bf(acc[2] * inv) | ((uint)f2bf(acc[3] * inv) << 16);
            u.z = (uint)f2bf(acc[4] * inv) | ((uint)f2bf(acc[5] * inv) << 16);
            u.w = (uint)f2bf(acc[6] * inv) | ((uint)f2bf(acc[7] * inv) << 16);
            *(uint4*)&((uint*)m1sh)[w * 68 + lr * 4] = u;
        }
    }
    __syncthreads();

    // A fragments: mean part (k<128) from LDS, x part from global (L1-broadcast across waves)
    bf16x8 afr[8];
#pragma unroll
    for (int ks = 0; ks < 8; ++ks) {
        int k0 = ks * 32;
        if (k0 < 128)
            afr[ks] = *(const bf16x8*)&m1sh[lr * 136 + k0 + lg * 8];
        else
            afr[ks] = *(const bf16x8*)(xb + row * 128 + (k0 - 128) + lg * 8);
    }

    // ---- gemm1: 16 rows x 16 cols per wave, epilogue to LDS ----
    {
        f32x4 acc = {};
#pragma unroll
        for (int ks = 0; ks < 8; ++ks) {
            int k0 = ks * 32;
            bf16x8 b = *(const bf16x8*)(W1T + col * 256 + k0 + lg * 8);
            acc = __builtin_amdgcn_mfma_f32_16x16x32_bf16(afr[ks], b, acc, 0, 0, 0);
        }
        float bias = b1[col];
#pragma unroll
        for (int i = 0; i < 4; ++i) {
            float v = acc[i] + bias;
            v = v > 0.f ? v : 0.f;
            hsh[(lg * 4 + i) * 264 + col] = f2bf(v);
        }
    }
    __syncthreads();

    // ---- gemm2 A fragments from LDS (rows lr, all 256 k) ----
    bf16x8 afr2[8];
#pragma unroll
    for (int ks = 0; ks < 8; ++ks)
        afr2[ks] = *(const bf16x8*)&hsh[lr * 264 + ks * 32 + lg * 8];

    // ---- gemm2: same 16 rows, cols c0..c0+15 ----
    {
        f32x4 acc = {};
#pragma unroll
        for (int ks = 0; ks < 8; ++ks) {
            int k0 = ks * 32;
            bf16x8 b = *(const bf16x8*)(W2T + col * 256 + k0 + lg * 8);
            acc = __builtin_amdgcn_mfma_f32_16x16x32_bf16(afr2[ks], b, acc, 0, 0, 0);
        }
        if (col < 128) {   // waves 0-7: wave-uniform branch
#pragma unroll
            for (int i = 0; i < 4; ++i)
                t[(r0 + lg * 4 + i) * 128 + col] = f2bf(acc[i]);
        } else {           // waves 8-15
            int oc = col - 128;
            float bias = b2[oc];
#pragma unroll
            for (int i = 0; i < 4; ++i)
                out[(r0 + lg * 4 + i) * 128 + oc] = acc[i] + bias;
        }
    }
}

// ---------------- launch ----------------

extern "C" void kernel_launch(void* const* d_in, const int* in_sizes, int n_in,
                              void* d_out, int out_size, void* d_ws, size_t ws_size,
                              hipStream_t stream) {
    const float* x   = (const float*)d_in[0];
    const int* edge  = (const int*)d_in[1];
    const float* W1l = (const float*)d_in[2];
    const float* W1r = (const float*)d_in[3];
    const float* b1  = (const float*)d_in[4];
    const float* W2l = (const float*)d_in[5];
    const float* W2r = (const float*)d_in[6];
    const float* b2  = (const float*)d_in[7];
    float* out = (float*)d_out;

    int E = in_sizes[1] / 2;
    const int* src = edge;
    const int* dst = edge + E;
    int chunk = (((E + HB - 1) / HB) + 3) & ~3;   // chunk multiple of 4

    // workspace layout
    ushort* tb   = (ushort*)d_ws;                         // [N,128] bf16 t (h@W2l)
    ushort* hb   = tb + (size_t)N_NODES * 128;            // [N,256] bf16 (layout spacer)
    ushort* xb   = hb + (size_t)N_NODES * 256;            // [N,128] bf16
    ushort* W1T  = xb + (size_t)N_NODES * 128;            // [256][256] bf16
    ushort* W2T  = W1T + 256 * 256;                       // [256][256] bf16
    ushort* csr  = W2T + 256 * 256;                       // [E]
    ushort* lrank= csr + E;                               // [E]
    int* chist   = (int*)(lrank + E);                     // [HB][N]
    int* row_ptr = chist + HB * N_NODES;                  // [N+1]
    int* aggv    = row_ptr + (N_NODES + 1);               // [64] lookback aggregates

    // fused prologue: hist (first, CSR critical path) + cast x (+ zero aggv) + tcast weights
    prep_kernel<<<HB + CAST_B + TCAST_B, 256, 0, stream>>>(x, W1l, W1r, W2l, W2r,
                                                           dst, E, chunk, chist, lrank,
                                                           xb, W1T, W2T, aggv);

    // CSR mid-chain: one kernel (decoupled lookback scan)
    csr_mid_kernel<<<(N_NODES + 255) / 256, 256, 0, stream>>>(chist, row_ptr, aggv);

    // scatter (atomic-free)
    scatter_kernel<<<(E / 4 + 255) / 256, 256, 0, stream>>>(src, dst, lrank, chist, E, chunk, csr);

    // fused mean1 + gemm1 + gemm2 (mean1 and h stay in LDS), 16 waves/block
    gemm_fused<<<N_NODES / 16, 1024, 0, stream>>>(xb, row_ptr, csr, W1T, b1, W2T, b2, tb, out);

    // layer 2 aggregation: out += segment_mean(t)
    agg_kernel<<<(N_NODES + 3) / 4, 256, 0, stream>>>(tb, row_ptr, csr, out);
}

// Round 15
// 91.287 us; speedup vs baseline: 1.1137x; 1.0149x over previous
//
#include <hip/hip_runtime.h>

#define N_NODES 10000
#define HB 128         // histogram chunks

typedef unsigned int uint;
typedef unsigned short ushort;
typedef __attribute__((ext_vector_type(8))) short bf16x8;
typedef __attribute__((ext_vector_type(4))) float f32x4;

__device__ __forceinline__ ushort f2bf(float f) {
    uint b = __float_as_uint(f);
    b += 0x7fffu + ((b >> 16) & 1u);
    return (ushort)(b >> 16);
}

// ---- wide gather-sum: branch-free counted main loop, 8x16B loads in flight ----
// lane l: edge-class l>>4, channels 8*(l&15)..+7. Full 32-edge blocks run unguarded
// (clean dataflow -> compiler keeps all 8 loads in flight); one guarded tail block.
#define ACCV(vv)                                                           \
    {                                                                      \
        _Pragma("unroll") for (int j = 0; j < 8; ++j)                      \
            acc[j] += __uint_as_float((uint)(ushort)vv[j] << 16);          \
    }

__device__ __forceinline__ void gather_sum16(int n, int lane, const ushort* __restrict__ feat,
                                             const int* __restrict__ row_ptr,
                                             const ushort* __restrict__ csr,
                                             float* acc, float* invdeg) {
    int beg = row_ptr[n], end = row_ptr[n + 1];
    int deg = end - beg;
    int ch0 = (lane & 15) * 8;
    int eo = lane >> 4;
#pragma unroll
    for (int j = 0; j < 8; ++j) acc[j] = 0.f;
    *invdeg = deg > 0 ? 1.0f / (float)deg : 0.0f;
    if (deg <= 0) return;
    int nfull = deg >> 5;          // full 32-edge blocks
    int i = beg;
    for (int b = 0; b < nfull; ++b, i += 32) {
        const ushort* cp = csr + i + eo;
        int s0 = cp[0];
        int s1 = cp[4];
        int s2 = cp[8];
        int s3 = cp[12];
        int s4 = cp[16];
        int s5 = cp[20];
        int s6 = cp[24];
        int s7 = cp[28];
        bf16x8 v0 = *(const bf16x8*)&feat[s0 * 128 + ch0];
        bf16x8 v1 = *(const bf16x8*)&feat[s1 * 128 + ch0];
        bf16x8 v2 = *(const bf16x8*)&feat[s2 * 128 + ch0];
        bf16x8 v3 = *(const bf16x8*)&feat[s3 * 128 + ch0];
        bf16x8 v4 = *(const bf16x8*)&feat[s4 * 128 + ch0];
        bf16x8 v5 = *(const bf16x8*)&feat[s5 * 128 + ch0];
        bf16x8 v6 = *(const bf16x8*)&feat[s6 * 128 + ch0];
        bf16x8 v7 = *(const bf16x8*)&feat[s7 * 128 + ch0];
        ACCV(v0) ACCV(v1) ACCV(v2) ACCV(v3)
        ACCV(v4) ACCV(v5) ACCV(v6) ACCV(v7)
    }
    if (i < end) {                 // tail (< 32 edges), clamped loads + guarded acc
        int last = end - 1;
        int b0 = i + eo;
        int s0 = csr[min(b0 + 0, last)];
        int s1 = csr[min(b0 + 4, last)];
        int s2 = csr[min(b0 + 8, last)];
        int s3 = csr[min(b0 + 12, last)];
        int s4 = csr[min(b0 + 16, last)];
        int s5 = csr[min(b0 + 20, last)];
        int s6 = csr[min(b0 + 24, last)];
        int s7 = csr[min(b0 + 28, last)];
        bf16x8 v0 = *(const bf16x8*)&feat[s0 * 128 + ch0];
        bf16x8 v1 = *(const bf16x8*)&feat[s1 * 128 + ch0];
        bf16x8 v2 = *(const bf16x8*)&feat[s2 * 128 + ch0];
        bf16x8 v3 = *(const bf16x8*)&feat[s3 * 128 + ch0];
        bf16x8 v4 = *(const bf16x8*)&feat[s4 * 128 + ch0];
        bf16x8 v5 = *(const bf16x8*)&feat[s5 * 128 + ch0];
        bf16x8 v6 = *(const bf16x8*)&feat[s6 * 128 + ch0];
        bf16x8 v7 = *(const bf16x8*)&feat[s7 * 128 + ch0];
        if (b0 + 0 < end)  ACCV(v0)
        if (b0 + 4 < end)  ACCV(v1)
        if (b0 + 8 < end)  ACCV(v2)
        if (b0 + 12 < end) ACCV(v3)
        if (b0 + 16 < end) ACCV(v4)
        if (b0 + 20 < end) ACCV(v5)
        if (b0 + 24 < end) ACCV(v6)
        if (b0 + 28 < end) ACCV(v7)
    }
    // reduce the 4 edge-classes (lanes l, l+16, l+32, l+48 share a channel-span)
#pragma unroll
    for (int j = 0; j < 8; ++j) {
        acc[j] += __shfl_xor(acc[j], 16);
        acc[j] += __shfl_xor(acc[j], 32);
    }
}

// ---------------- fused prologue ----------------
// blocks [0, HB)            : per-chunk LDS histogram + local rank (CSR critical path, first)
// blocks [HB, HB+CAST_B)    : xb = bf16(x)   (block HB also zeroes aggv flags)
// blocks [HB+CAST_B, ...)   : W1T/W2T transpose-cast (one c per block; writes coalesced)
#define CAST_B 1250   // N_NODES*128/4 / 256
#define TCAST_B 512   // 2*65536 / 256

__global__ __launch_bounds__(256) void prep_kernel(const float* __restrict__ x,
                                                   const float* __restrict__ W1l,
                                                   const float* __restrict__ W1r,
                                                   const float* __restrict__ W2l,
                                                   const float* __restrict__ W2r,
                                                   const int* __restrict__ dst, int E, int chunk,
                                                   int* __restrict__ chunk_hist,
                                                   ushort* __restrict__ lrank,
                                                   ushort* __restrict__ xb,
                                                   ushort* __restrict__ W1T,
                                                   ushort* __restrict__ W2T,
                                                   int* __restrict__ aggv) {
    __shared__ int hist[N_NODES];   // 40 KB
    int b = blockIdx.x;
    int t = threadIdx.x;
    if (b < HB) {
        int4* h4 = (int4*)hist;
        for (int i = t; i < N_NODES / 4; i += 256) h4[i] = make_int4(0, 0, 0, 0);
        __syncthreads();
        int e0 = b * chunk;
        int e1 = e0 + chunk; if (e1 > E) e1 = E;
        for (int e = e0 + t; e < e1; e += 256) {
            int d = dst[e];
            lrank[e] = (ushort)atomicAdd(&hist[d], 1);
        }
        __syncthreads();
        int4* c4 = (int4*)(chunk_hist + b * N_NODES);
        for (int i = t; i < N_NODES / 4; i += 256) c4[i] = h4[i];
    } else if (b < HB + CAST_B) {
        if (b == HB && t < 64) aggv[t] = 0;    // zero lookback flags for csr_mid
        int i = (b - HB) * 256 + t;
        float4 v = ((const float4*)x)[i];
        ushort4 o;
        o.x = f2bf(v.x); o.y = f2bf(v.y); o.z = f2bf(v.z); o.w = f2bf(v.w);
        ((ushort4*)xb)[i] = o;
    } else {
        // transpose-cast, write-coalesced: one virtual column c per block, thread t = k.
        int id = b - HB - CAST_B;      // 0..511
        int z = id >> 8;               // 0: W1T, 1: W2T
        int c = id & 255;
        int k = t;
        if (z == 0) {
            // W1T[c][k] = k<128 ? W1l[k][c] : W1r[k-128][c]
            float v = (k < 128) ? W1l[k * 256 + c] : W1r[(k - 128) * 256 + c];
            W1T[c * 256 + k] = f2bf(v);
        } else {
            // W2T[c][k] = c<128 ? W2l[k][c] : W2r[k][c-128]
            float v = (c < 128) ? W2l[k * 128 + c] : W2r[k * 128 + (c - 128)];
            W2T[c * 256 + k] = f2bf(v);
        }
    }
}

// ---------------- CSR mid-chain, fused: colsum + scan (decoupled lookback) + offs ----------------
__global__ __launch_bounds__(256) void csr_mid_kernel(int* __restrict__ ch,
                                                      int* __restrict__ row_ptr,
                                                      int* __restrict__ aggv) {
    int b = blockIdx.x, t = threadIdx.x;
    int n = b * 256 + t;
    bool ok = n < N_NODES;
    int s = 0;
    if (ok) {
#pragma unroll 8
        for (int c = 0; c < HB; ++c) s += ch[c * N_NODES + n];
    }
    // block-wide inclusive scan
    int lane = t & 63, wid = t >> 6;
    int incl = s;
#pragma unroll
    for (int off = 1; off < 64; off <<= 1) {
        int y = __shfl_up(incl, off);
        if (lane >= off) incl += y;
    }
    __shared__ int wsum[4];
    __shared__ int sbase;
    if (lane == 63) wsum[wid] = incl;
    __syncthreads();
    int tot = wsum[0] + wsum[1] + wsum[2] + wsum[3];
    int wbase = 0;
#pragma unroll
    for (int w = 0; w < 4; ++w)
        if (w < wid) wbase += wsum[w];
    incl += wbase;
    // publish aggregate FIRST (no circular wait), then look back
    if (t == 0)
        __hip_atomic_store(&aggv[b], tot + 1, __ATOMIC_RELEASE, __HIP_MEMORY_SCOPE_AGENT);
    if (t < 64) {
        int v = 0;
        if (t < b) {
            do {
                v = __hip_atomic_load(&aggv[t], __ATOMIC_ACQUIRE, __HIP_MEMORY_SCOPE_AGENT);
            } while (v == 0);
            --v;
        }
#pragma unroll
        for (int m = 1; m < 64; m <<= 1) v += __shfl_xor(v, m);
        if (t == 0) sbase = v;
    }
    __syncthreads();
    int base = sbase;
    if (b == 0 && t == 0) row_ptr[0] = 0;
    if (ok) {
        row_ptr[n + 1] = base + incl;
        int run = base + incl - s;      // exclusive prefix = global start of node n
#pragma unroll 8
        for (int c = 0; c < HB; ++c) {
            int v = ch[c * N_NODES + n];
            ch[c * N_NODES + n] = run;
            run += v;
        }
    }
}

// ---------------- atomic-free scatter ----------------
__global__ __launch_bounds__(256) void scatter_kernel(const int* __restrict__ src,
                                                      const int* __restrict__ dst,
                                                      const ushort* __restrict__ lrank,
                                                      const int* __restrict__ off,
                                                      int E, int chunk,
                                                      ushort* __restrict__ csr) {
    int g = blockIdx.x * blockDim.x + threadIdx.x;
    int e = g * 4;
    if (e + 3 < E) {
        int b = e / chunk;                    // chunk is multiple of 4, so uniform for the 4-group
        const int* ob = off + b * N_NODES;
        int4 d = *(const int4*)&dst[e];
        int4 s = *(const int4*)&src[e];
        ushort4 r = *(const ushort4*)&lrank[e];
        csr[ob[d.x] + r.x] = (ushort)s.x;
        csr[ob[d.y] + r.y] = (ushort)s.y;
        csr[ob[d.z] + r.z] = (ushort)s.z;
        csr[ob[d.w] + r.w] = (ushort)s.w;
    } else {
        for (; e < E; ++e)
            csr[off[(e / chunk) * N_NODES + dst[e]] + lrank[e]] = (ushort)src[e];
    }
}

// ---------------- layer-2 aggregation: out += segment_mean(t) ----------------
__global__ __launch_bounds__(256) void agg_kernel(const ushort* __restrict__ feat,
                                                  const int* __restrict__ row_ptr,
                                                  const ushort* __restrict__ csr,
                                                  float* __restrict__ out) {
    int wave = threadIdx.x >> 6;
    int lane = threadIdx.x & 63;
    int n = blockIdx.x * 4 + wave;
    if (n >= N_NODES) return;
    float acc[8], inv;
    gather_sum16(n, lane, feat, row_ptr, csr, acc, &inv);
    if ((lane >> 4) == 0) {   // lanes 0-15: 32B contiguous per lane, 512B per row
        float4* o = (float4*)&out[n * 128 + (lane & 15) * 8];
        float4 a = o[0], b = o[1];
        a.x += acc[0] * inv; a.y += acc[1] * inv; a.z += acc[2] * inv; a.w += acc[3] * inv;
        b.x += acc[4] * inv; b.y += acc[5] * inv; b.z += acc[6] * inv; b.w += acc[7] * inv;
        o[0] = a; o[1] = b;
    }
}

// ---------------- fused mean1 + GEMM1 + GEMM2: 16-row panels, 16 waves ----------------
// grid = 625 blocks x 1024 threads. Block owns rows r0..r0+15.
// phase 0: wave w computes mean1 for ONE node r0+w -> LDS m1sh  (10000 gather waves total)
// phase 1 (gemm1): wave w owns 16-col strip c0=w*16: h = relu([mean1|x]@W1T^T+b1) -> LDS hsh
// phase 2 (gemm2): same strip; waves 0-7 -> t = bf16(h@W2l); waves 8-15 -> out = h@W2r+b2
__global__ __launch_bounds__(1024, 8) void gemm_fused(const ushort* __restrict__ xb,
                                                      const int* __restrict__ row_ptr,
                                                      const ushort* __restrict__ csr,
                                                      const ushort* __restrict__ W1T,
                                                      const float* __restrict__ b1,
                                                      const ushort* __restrict__ W2T,
                                                      const float* __restrict__ b2,
                                                      ushort* __restrict__ t,
                                                      float* __restrict__ out) {
    __shared__ ushort hsh[16 * 264];    // 8.25 KB
    __shared__ ushort m1sh[16 * 136];   // 4.25 KB
    int w = threadIdx.x >> 6, lane = threadIdx.x & 63;
    int lr = lane & 15, lg = lane >> 4;
    int r0 = blockIdx.x * 16;
    int row = r0 + lr;
    int c0 = w * 16;   // this wave's 16-column strip
    int col = c0 + lr;

    // ---- phase 0: mean1 for node r0+w (one node per wave, pipelined 16B/lane gather) ----
    {
        float acc[8], inv;
        gather_sum16(r0 + w, lane, xb, row_ptr, csr, acc, &inv);
        if (lg == 0) {   // lanes 0-15: pack 8 channels -> uint4, 16B contiguous per lane
            uint4 u;
            u.x = (uint)f2bf(acc[0] * inv) | ((uint)f2bf(acc[1] * inv) << 16);
            u.y = (uint)f2bf(acc[2] * inv) | ((uint)f2bf(acc[3] * inv) << 16);
            u.z = (uint)f2bf(acc[4] * inv) | ((uint)f2bf(acc[5] * inv) << 16);
            u.w = (uint)f2bf(acc[6] * inv) | ((uint)f2bf(acc[7] * inv) << 16);
            *(uint4*)&((uint*)m1sh)[w * 68 + lr * 4] = u;
        }
    }
    __syncthreads();

    // A fragments: mean part (k<128) from LDS, x part from global (L1-broadcast across waves)
    bf16x8 afr[8];
#pragma unroll
    for (int ks = 0; ks < 8; ++ks) {
        int k0 = ks * 32;
        if (k0 < 128)
            afr[ks] = *(const bf16x8*)&m1sh[lr * 136 + k0 + lg * 8];
        else
            afr[ks] = *(const bf16x8*)(xb + row * 128 + (k0 - 128) + lg * 8);
    }

    // ---- gemm1: 16 rows x 16 cols per wave, epilogue to LDS ----
    {
        f32x4 acc = {};
#pragma unroll
        for (int ks = 0; ks < 8; ++ks) {
            int k0 = ks * 32;
            bf16x8 b = *(const bf16x8*)(W1T + col * 256 + k0 + lg * 8);
            acc = __builtin_amdgcn_mfma_f32_16x16x32_bf16(afr[ks], b, acc, 0, 0, 0);
        }
        float bias = b1[col];
#pragma unroll
        for (int i = 0; i < 4; ++i) {
            float v = acc[i] + bias;
            v = v > 0.f ? v : 0.f;
            hsh[(lg * 4 + i) * 264 + col] = f2bf(v);
        }
    }
    __syncthreads();

    // ---- gemm2 A fragments from LDS (rows lr, all 256 k) ----
    bf16x8 afr2[8];
#pragma unroll
    for (int ks = 0; ks < 8; ++ks)
        afr2[ks] = *(const bf16x8*)&hsh[lr * 264 + ks * 32 + lg * 8];

    // ---- gemm2: same 16 rows, cols c0..c0+15 ----
    {
        f32x4 acc = {};
#pragma unroll
        for (int ks = 0; ks < 8; ++ks) {
            int k0 = ks * 32;
            bf16x8 b = *(const bf16x8*)(W2T + col * 256 + k0 + lg * 8);
            acc = __builtin_amdgcn_mfma_f32_16x16x32_bf16(afr2[ks], b, acc, 0, 0, 0);
        }
        if (col < 128) {   // waves 0-7: wave-uniform branch
#pragma unroll
            for (int i = 0; i < 4; ++i)
                t[(r0 + lg * 4 + i) * 128 + col] = f2bf(acc[i]);
        } else {           // waves 8-15
            int oc = col - 128;
            float bias = b2[oc];
#pragma unroll
            for (int i = 0; i < 4; ++i)
                out[(r0 + lg * 4 + i) * 128 + oc] = acc[i] + bias;
        }
    }
}

// ---------------- launch ----------------

extern "C" void kernel_launch(void* const* d_in, const int* in_sizes, int n_in,
                              void* d_out, int out_size, void* d_ws, size_t ws_size,
                              hipStream_t stream) {
    const float* x   = (const float*)d_in[0];
    const int* edge  = (const int*)d_in[1];
    const float* W1l = (const float*)d_in[2];
    const float* W1r = (const float*)d_in[3];
    const float* b1  = (const float*)d_in[4];
    const float* W2l = (const float*)d_in[5];
    const float* W2r = (const float*)d_in[6];
    const float* b2  = (const float*)d_in[7];
    float* out = (float*)d_out;

    int E = in_sizes[1] / 2;
    const int* src = edge;
    const int* dst = edge + E;
    int chunk = (((E + HB - 1) / HB) + 3) & ~3;   // chunk multiple of 4

    // workspace layout
    ushort* tb   = (ushort*)d_ws;                         // [N,128] bf16 t (h@W2l)
    ushort* hb   = tb + (size_t)N_NODES * 128;            // [N,256] bf16 (layout spacer)
    ushort* xb   = hb + (size_t)N_NODES * 256;            // [N,128] bf16
    ushort* W1T  = xb + (size_t)N_NODES * 128;            // [256][256] bf16
    ushort* W2T  = W1T + 256 * 256;                       // [256][256] bf16
    ushort* csr  = W2T + 256 * 256;                       // [E]
    ushort* lrank= csr + E;                               // [E]
    int* chist   = (int*)(lrank + E);                     // [HB][N]
    int* row_ptr = chist + HB * N_NODES;                  // [N+1]
    int* aggv    = row_ptr + (N_NODES + 1);               // [64] lookback aggregates

    // fused prologue: hist (first, CSR critical path) + cast x (+ zero aggv) + tcast weights
    prep_kernel<<<HB + CAST_B + TCAST_B, 256, 0, stream>>>(x, W1l, W1r, W2l, W2r,
                                                           dst, E, chunk, chist, lrank,
                                                           xb, W1T, W2T, aggv);

    // CSR mid-chain: one kernel (decoupled lookback scan)
    csr_mid_kernel<<<(N_NODES + 255) / 256, 256, 0, stream>>>(chist, row_ptr, aggv);

    // scatter (atomic-free)
    scatter_kernel<<<(E / 4 + 255) / 256, 256, 0, stream>>>(src, dst, lrank, chist, E, chunk, csr);

    // fused mean1 + gemm1 + gemm2 (mean1 and h stay in LDS), 16 waves/block
    gemm_fused<<<N_NODES / 16, 1024, 0, stream>>>(xb, row_ptr, csr, W1T, b1, W2T, b2, tb, out);

    // layer 2 aggregation: out += segment_mean(t)
    agg_kernel<<<(N_NODES + 3) / 4, 256, 0, stream>>>(tb, row_ptr, csr, out);
}